// Round 3
// baseline (460.593 us; speedup 1.0000x reference)
//
#include <hip/hip_runtime.h>
#include <stdint.h>

#define N_NODES 2048
#define DIM 1024
#define BATCH 16384
#define NEDGE 65536
#define CAP 96

typedef __bf16 bf16x8 __attribute__((ext_vector_type(8)));
typedef float f32x4 __attribute__((ext_vector_type(4)));
typedef unsigned short u16;
typedef unsigned int u32;

__device__ __forceinline__ u16 f2bf(float f) {
  union { float f; u32 i; } v; v.f = f;
  u32 r = v.i + 0x7fffu + ((v.i >> 16) & 1u);
  return (u16)(r >> 16);
}

// ---------- detect int64-vs-int32 index array ----------
__global__ void k_detect(const int* __restrict__ dx, int* __restrict__ flag) {
  if (threadIdx.x == 0 && blockIdx.x == 0) {
    int is64 = 1;
    for (int j = 0; j < 32; ++j)
      if (dx[2 * j + 1] != 0) { is64 = 0; break; }
    *flag = is64;
  }
}

__global__ __launch_bounds__(256) void k_cvt(const int* __restrict__ dx,
                                             const int* __restrict__ flag,
                                             int* __restrict__ idx) {
  int i = blockIdx.x * 256 + threadIdx.x;
  if (i >= 7 * BATCH) return;
  int v = (*flag) ? dx[2 * i] : dx[i];
  idx[i] = v & (N_NODES - 1);
}

// ---------- stage 1: bucket fill ----------
__global__ __launch_bounds__(256) void k_bucket(const int* __restrict__ idx,
                                                int* __restrict__ counts,
                                                int* __restrict__ bucket) {
  int i = blockIdx.x * 256 + threadIdx.x;
  if (i >= 2 * BATCH) return;
  int n = (i < BATCH) ? idx[7 * i] : idx[7 * (i - BATCH) + 1];
  int slot = atomicAdd(&counts[n], 1);
  if (slot < CAP) bucket[n * CAP + slot] = i;
}

// ---------- stage 2: per-node segment sum (f32 in) -> A1 (bf16) ----------
__global__ __launch_bounds__(256) void k_nodesum(const float* __restrict__ feat,
                                                 const int* __restrict__ counts,
                                                 const int* __restrict__ bucket,
                                                 u16* __restrict__ A1) {
  int n = blockIdx.x;
  int tid = threadIdx.x;
  int cnt = counts[n]; if (cnt > CAP) cnt = CAP;
  float a0 = 0.f, a1 = 0.f, a2 = 0.f, a3 = 0.f;
  for (int j = 0; j < cnt; ++j) {
    int i = bucket[n * CAP + j];
    size_t rowoff = (i < BATCH) ? ((size_t)i * 7) * DIM
                                : ((size_t)(i - BATCH) * 7 + 1) * DIM;
    f32x4 v = *(const f32x4*)(feat + rowoff + tid * 4);
    a0 += v[0]; a1 += v[1]; a2 += v[2]; a3 += v[3];
  }
  ushort4 o; o.x = f2bf(a0); o.y = f2bf(a1); o.z = f2bf(a2); o.w = f2bf(a3);
  *(ushort4*)(A1 + (size_t)n * DIM + tid * 4) = o;
}

// ---------- weight transpose (K x N, f32) -> (N x K, bf16) ----------
__global__ __launch_bounds__(256) void k_transpose(const float* __restrict__ W,
                                                   u16* __restrict__ Wt,
                                                   int K, int N) {
  __shared__ __align__(16) u16 t[32][33];
  int ntx = N >> 5;
  int bx = blockIdx.x % ntx;
  int by = blockIdx.x / ntx;
  int tx = threadIdx.x & 31, ty = threadIdx.x >> 5;  // 32 x 8
  #pragma unroll
  for (int r = 0; r < 32; r += 8)
    t[r + ty][tx] = f2bf(W[(size_t)(by * 32 + r + ty) * N + bx * 32 + tx]);
  __syncthreads();
  #pragma unroll
  for (int r = 0; r < 32; r += 8)
    Wt[(size_t)(bx * 32 + r + ty) * K + by * 32 + tx] = t[tx][r + ty];
}

// ---------- CSR row_ptr via binary search over sorted adj_rows ----------
__global__ __launch_bounds__(256) void k_rowptr(const int* __restrict__ adj_rows,
                                                int* __restrict__ row_ptr) {
  int r = blockIdx.x * 256 + threadIdx.x;
  if (r > N_NODES) return;
  int lo = 0, hi = NEDGE;
  while (lo < hi) { int mid = (lo + hi) >> 1; if (adj_rows[mid] < r) lo = mid + 1; else hi = mid; }
  row_ptr[r] = lo;
}

// ---------- MFMA GEMM: C(MxN,f32) = A(MxK,bf16) * Bt(NxK,bf16)^T ----------
__global__ __launch_bounds__(256) void k_gemm_bt(const u16* __restrict__ A,
                                                 const u16* __restrict__ Bt,
                                                 float* __restrict__ C,
                                                 int M, int N, int K) {
  __shared__ __align__(16) u16 As[128 * 32];
  __shared__ __align__(16) u16 Bs[128 * 32];
  const int ntx = N >> 7;
  const int bx = blockIdx.x % ntx;
  const int by = blockIdx.x / ntx;
  const int tid = threadIdx.x;
  const int wid = tid >> 6;
  const int lane = tid & 63;
  const int wr = wid >> 1, wc = wid & 1;  // 2x2 waves, 64x64 each
  const int rowbase = by * 128, colbase = bx * 128;

  f32x4 acc[4][4];
  #pragma unroll
  for (int i = 0; i < 4; ++i)
    #pragma unroll
    for (int j = 0; j < 4; ++j) acc[i][j] = (f32x4){0.f, 0.f, 0.f, 0.f};

  const int lrow = lane >> 2;         // 16 rows per 1KB chunk
  const int lkk = (lane & 3) * 8;     // 4 x 16B per row

  for (int kt = 0; kt < K; kt += 32) {
    #pragma unroll
    for (int i = 0; i < 2; ++i) {
      int c = i * 4 + wid;            // chunk 0..7 (1KB each)
      int row = c * 16 + lrow;
      const u16* gA = A + (size_t)(rowbase + row) * K + kt + lkk;
      __builtin_amdgcn_global_load_lds(
          (const __attribute__((address_space(1))) u32*)gA,
          (__attribute__((address_space(3))) u32*)(As + c * 512), 16, 0, 0);
      const u16* gB = Bt + (size_t)(colbase + row) * K + kt + lkk;
      __builtin_amdgcn_global_load_lds(
          (const __attribute__((address_space(1))) u32*)gB,
          (__attribute__((address_space(3))) u32*)(Bs + c * 512), 16, 0, 0);
    }
    __syncthreads();  // drains vmcnt (global_load_lds) before use
    bf16x8 af[4], bfr[4];
    #pragma unroll
    for (int mi = 0; mi < 4; ++mi) {
      int row = wr * 64 + mi * 16 + (lane & 15);
      af[mi] = *(const bf16x8*)(As + row * 32 + (lane >> 4) * 8);
    }
    #pragma unroll
    for (int ni = 0; ni < 4; ++ni) {
      int col = wc * 64 + ni * 16 + (lane & 15);
      bfr[ni] = *(const bf16x8*)(Bs + col * 32 + (lane >> 4) * 8);
    }
    #pragma unroll
    for (int mi = 0; mi < 4; ++mi)
      #pragma unroll
      for (int ni = 0; ni < 4; ++ni)
        acc[mi][ni] = __builtin_amdgcn_mfma_f32_16x16x32_bf16(af[mi], bfr[ni], acc[mi][ni], 0, 0, 0);
    __syncthreads();  // protect LDS before next iteration overwrites
  }

  #pragma unroll
  for (int mi = 0; mi < 4; ++mi) {
    #pragma unroll
    for (int ni = 0; ni < 4; ++ni) {
      int col = colbase + wc * 64 + ni * 16 + (lane & 15);
      #pragma unroll
      for (int j = 0; j < 4; ++j) {
        int row = rowbase + wr * 64 + mi * 16 + (lane >> 4) * 4 + j;
        C[(size_t)row * N + col] = acc[mi][ni][j];
      }
    }
  }
}

// ---------- SpMM (CSR) + bias + optional relu ----------
// X f32 in; writes bf16 Y16 (for next GEMM) or f32 Y32 (final logits)
__global__ __launch_bounds__(256) void k_spmm(const float* __restrict__ X,
                                              const int* __restrict__ row_ptr,
                                              const int* __restrict__ adj_cols,
                                              const float* __restrict__ adj_vals,
                                              const float* __restrict__ bias,
                                              u16* __restrict__ Y16,
                                              float* __restrict__ Y32,
                                              int width, int do_relu) {
  int chunks = width >> 10;
  int r = blockIdx.x / chunks;
  int ch = blockIdx.x - r * chunks;
  int col = ch * 1024 + threadIdx.x * 4;
  int e0 = row_ptr[r], e1 = row_ptr[r + 1];
  float a0 = 0.f, a1 = 0.f, a2 = 0.f, a3 = 0.f;
  for (int e = e0; e < e1; ++e) {
    int c = adj_cols[e] & (N_NODES - 1);
    float v = adj_vals[e];
    f32x4 x = *(const f32x4*)(X + (size_t)c * width + col);
    a0 += v * x[0]; a1 += v * x[1]; a2 += v * x[2]; a3 += v * x[3];
  }
  f32x4 bb = *(const f32x4*)(bias + col);
  a0 += bb[0]; a1 += bb[1]; a2 += bb[2]; a3 += bb[3];
  if (do_relu) {
    a0 = fmaxf(a0, 0.f); a1 = fmaxf(a1, 0.f);
    a2 = fmaxf(a2, 0.f); a3 = fmaxf(a3, 0.f);
  }
  if (Y16) {
    ushort4 o; o.x = f2bf(a0); o.y = f2bf(a1); o.z = f2bf(a2); o.w = f2bf(a3);
    *(ushort4*)(Y16 + (size_t)r * width + col) = o;
  } else {
    f32x4 o; o[0] = a0; o[1] = a1; o[2] = a2; o[3] = a3;
    *(f32x4*)(Y32 + (size_t)r * width + col) = o;
  }
}

// ---------- output assembly (all f32) ----------
__global__ __launch_bounds__(256) void k_assemble(const float* __restrict__ feat,
                                                  const float* __restrict__ logits,
                                                  const int* __restrict__ idx,
                                                  float* __restrict__ out) {
  int i = blockIdx.x;  // 0 .. B*7-1
  int b = i / 7, slot = i - b * 7;
  const float* src;
  if (slot == 0)      src = logits + (size_t)idx[7 * b + 1] * DIM;  // e2
  else if (slot == 1) src = logits + (size_t)idx[7 * b] * DIM;      // e1
  else                src = feat + ((size_t)b * 7 + slot) * DIM;
  f32x4 v = *(const f32x4*)(src + threadIdx.x * 4);
  *(f32x4*)(out + ((size_t)b * 7 + slot) * DIM + threadIdx.x * 4) = v;
}

extern "C" void kernel_launch(void* const* d_in, const int* in_sizes, int n_in,
                              void* d_out, int out_size, void* d_ws, size_t ws_size,
                              hipStream_t stream) {
  const float* feat   = (const float*)d_in[0];
  const int* data_x   = (const int*)d_in[1];
  const int* adj_rows = (const int*)d_in[2];
  const int* adj_cols = (const int*)d_in[3];
  const float* adj_vals = (const float*)d_in[4];
  const float* W1 = (const float*)d_in[5];
  const float* b1 = (const float*)d_in[6];
  const float* W2 = (const float*)d_in[7];
  const float* b2 = (const float*)d_in[8];
  const float* W3 = (const float*)d_in[9];
  const float* b3 = (const float*)d_in[10];
  float* out = (float*)d_out;

  char* ws = (char*)d_ws;
  size_t off = 0;
  auto alloc = [&](size_t bytes) {
    char* p = ws + off; off += (bytes + 511) & ~(size_t)511; return p;
  };
  int*  flag    = (int*)alloc(4);
  int*  idx32   = (int*)alloc((size_t)7 * BATCH * 4);
  int*  counts  = (int*)alloc(N_NODES * 4);
  int*  bucket  = (int*)alloc((size_t)N_NODES * CAP * 4);
  int*  row_ptr = (int*)alloc((N_NODES + 1) * 4);
  u16*  A1      = (u16*)alloc((size_t)N_NODES * DIM * 2);        // 4 MB
  u16*  Wt      = (u16*)alloc((size_t)N_NODES * N_NODES * 2);    // 8 MB, reused per layer
  float* X      = (float*)alloc((size_t)N_NODES * N_NODES * 4);  // 16 MB, reused X1/X2/X3
  u16*  Hbuf    = (u16*)alloc((size_t)N_NODES * N_NODES * 2);    // 8 MB, H1 then H2
  float* logits = (float*)alloc((size_t)N_NODES * DIM * 4);      // 8 MB
  // peak ws use ~= 46 MB

  hipMemsetAsync(counts, 0, N_NODES * 4, stream);
  k_detect<<<1, 64, 0, stream>>>(data_x, flag);
  k_cvt<<<(7 * BATCH + 255) / 256, 256, 0, stream>>>(data_x, flag, idx32);
  k_bucket<<<(2 * BATCH + 255) / 256, 256, 0, stream>>>(idx32, counts, bucket);
  k_nodesum<<<N_NODES, 256, 0, stream>>>(feat, counts, bucket, A1);
  k_rowptr<<<N_NODES / 256 + 1, 256, 0, stream>>>(adj_rows, row_ptr);

  // layer 1: X = A1 @ W1 ; H1 = relu(spmm(X) + b1)
  k_transpose<<<(N_NODES / 32) * (DIM / 32), 256, 0, stream>>>(W1, Wt, DIM, N_NODES);
  k_gemm_bt<<<(N_NODES / 128) * (N_NODES / 128), 256, 0, stream>>>(A1, Wt, X, N_NODES, N_NODES, DIM);
  k_spmm<<<N_NODES * (N_NODES / 1024), 256, 0, stream>>>(X, row_ptr, adj_cols, adj_vals, b1, Hbuf, nullptr, N_NODES, 1);
  // layer 2: X = H1 @ W2 ; H2 = spmm(X) + b2
  k_transpose<<<(N_NODES / 32) * (N_NODES / 32), 256, 0, stream>>>(W2, Wt, N_NODES, N_NODES);
  k_gemm_bt<<<(N_NODES / 128) * (N_NODES / 128), 256, 0, stream>>>(Hbuf, Wt, X, N_NODES, N_NODES, N_NODES);
  k_spmm<<<N_NODES * (N_NODES / 1024), 256, 0, stream>>>(X, row_ptr, adj_cols, adj_vals, b2, Hbuf, nullptr, N_NODES, 0);
  // layer 3: X = H2 @ W3 ; logits = spmm(X) + b3 (f32 out)
  k_transpose<<<(DIM / 32) * (N_NODES / 32), 256, 0, stream>>>(W3, Wt, N_NODES, DIM);
  k_gemm_bt<<<(N_NODES / 128) * (DIM / 128), 256, 0, stream>>>(Hbuf, Wt, X, N_NODES, DIM, N_NODES);
  k_spmm<<<N_NODES * (DIM / 1024), 256, 0, stream>>>(X, row_ptr, adj_cols, adj_vals, b3, nullptr, logits, DIM, 0);

  k_assemble<<<BATCH * 7, 256, 0, stream>>>(feat, logits, idx32, out);
}